// Round 9
// baseline (97.783 us; speedup 1.0000x reference)
//
#include <hip/hip_runtime.h>

// Decoder: 2-layer LSTM (H=32) + MLP (96), B=16384, 25 steps.
// R9: single-wave fully-register-resident recurrence.
//  - Wcomb = Wih0@Wmlp (prep kernel -> d_ws) removes MLP from the chain.
//  - K-column permutation pi(kq*8+j)=4j+kq makes every C-frag -> B-frag
//    handoff lane-local: no LDS, no barriers, no shuffles in the t-loop.
//  - Weights in VGPR frags (128 regs); Wm + biases in LDS (broadcast).
//  - exp2-prescaled gates (R7/R8-proved). Inputs/outputs f32 (R2-proved).

#define PRED 25
#define BATCH 16384

typedef unsigned short u16;
typedef unsigned int   u32;
typedef __attribute__((ext_vector_type(8))) short bf16x8;
typedef __attribute__((ext_vector_type(4))) float f32x4;

#define LOG2E  1.44269504088896340736f
#define LOG2E2 2.88539008177792681472f

__device__ __forceinline__ float rcp_(float x){ return __builtin_amdgcn_rcpf(x); }
__device__ __forceinline__ float ex2(float x){ return __builtin_amdgcn_exp2f(x); }
__device__ __forceinline__ float sigm2(float xp){ return rcp_(1.0f + ex2(-xp)); }
__device__ __forceinline__ float tanh2(float xp){ return 1.0f - 2.0f*rcp_(ex2(xp) + 1.0f); }

__device__ __forceinline__ u16 f2b(float f){
  u32 i = __float_as_uint(f);
  i += 0x7FFFu + ((i >> 16) & 1u);
  return (u16)(i >> 16);
}
__device__ __forceinline__ float b2f(u16 u){ return __uint_as_float(((u32)u) << 16); }

__device__ __forceinline__ float act_h(f32x4 g, float& c){
  float ig = sigm2(g[0]);
  float fg = sigm2(g[1]);
  float gg = tanh2(g[2]);
  float og = sigm2(g[3]);
  c = fmaf(fg, c, ig*gg);
  return og * tanh2(c*LOG2E2);
}

__device__ __forceinline__ bf16x8 packh(const float* h){
  union{bf16x8 v; u16 s[8];} r;
  #pragma unroll
  for (int j = 0; j < 8; ++j) r.s[j] = f2b(h[j]);
  return r.v;
}
__device__ __forceinline__ void pack_hilo(const float* h, bf16x8& hi, bf16x8& lo){
  union{bf16x8 v; u16 s[8];} H, L;
  #pragma unroll
  for (int j = 0; j < 8; ++j){
    u16 x = f2b(h[j]);
    H.s[j] = x;
    L.s[j] = f2b(h[j] - b2f(x));
  }
  hi = H.v; lo = L.v;
}

// ---------- prep: Wcomb[128][32] = Wih0 @ Wmlp ; bcomb[128] ----------
extern "C" __global__ void prep_kernel(const float* __restrict__ Wih0,
                                       const float* __restrict__ Wmlp,
                                       const float* __restrict__ bih0,
                                       const float* __restrict__ bhh0,
                                       const float* __restrict__ bmlp,
                                       float* __restrict__ ws){
  int idx = blockIdx.x*256 + threadIdx.x;
  if (idx < 4096){
    int g = idx >> 5, u = idx & 31;
    const float* wr = Wih0 + g*96;
    const float* wc = Wmlp + u;
    float a = 0.f;
    #pragma unroll 8
    for (int p = 0; p < 96; ++p) a = fmaf(wr[p], wc[p*32], a);
    ws[idx] = a;
  } else if (idx < 4224){
    int g = idx - 4096;
    const float* wr = Wih0 + g*96;
    float a = bih0[g] + bhh0[g];
    #pragma unroll 8
    for (int p = 0; p < 96; ++p) a = fmaf(wr[p], bmlp[p], a);
    ws[idx] = a;
  }
}

// ---------- main ----------
struct __align__(16) SM {
  float b00[128];    // [i*16+kq*4+r] t=0 gates0 bias, scaled
  float bcomb[128];  // composed gates0 bias, scaled
  float b1[128];     // gates1 bias, scaled
  float bm[96];      // MLP bias (natural)
  u16   wmf[6*64*8]; // Wm frags (pi-permuted), [im][lane][8]
};

extern "C" __global__ __launch_bounds__(64, 1)
void decoder_kernel(const float* __restrict__ obs,  const float* __restrict__ lat,
                    const float* __restrict__ Wfc,  const float* __restrict__ bfc,
                    const float* __restrict__ Wih0, const float* __restrict__ Whh0,
                    const float* __restrict__ bih0, const float* __restrict__ bhh0,
                    const float* __restrict__ Wih1, const float* __restrict__ Whh1,
                    const float* __restrict__ bih1, const float* __restrict__ bhh1,
                    const float* __restrict__ Wmlp, const float* __restrict__ bmlp,
                    const float* __restrict__ ws,   float* __restrict__ out)
{
  __shared__ SM sm;
  const int l  = threadIdx.x;
  const int lr = l & 15;      // e within wave / frag row
  const int kq = l >> 4;      // k-quad
  const int ebase = blockIdx.x * 16;

  // ---- stage biases (scaled) + Wm frags into LDS ----
  for (int v = l; v < 128; v += 64){
    int r = v & 3, u = v >> 2;          // v = i*16+kq*4+r ; u = i*4+kq
    int g = r*32 + u;
    float sc = (r == 2) ? LOG2E2 : LOG2E;
    sm.b00[v]   = (bih0[g] + bhh0[g])*sc;
    sm.bcomb[v] = ws[4096 + g]*sc;
    sm.b1[v]    = (bih1[g] + bhh1[g])*sc;
  }
  for (int v = l; v < 96; v += 64) sm.bm[v] = bmlp[v];
  #pragma unroll
  for (int im = 0; im < 6; ++im){
    int o = im*16 + lr;
    union{bf16x8 v; u16 s[8];} fr;
    #pragma unroll
    for (int j = 0; j < 8; ++j) fr.s[j] = f2b(Wmlp[o*32 + 4*j + kq]);
    *(bf16x8*)&sm.wmf[(im*64 + l)*8] = fr.v;
  }
  __syncthreads();

  // ---- persistent weight frags (pi-permuted K, gate-permuted M, scaled) ----
  bf16x8 wcombf[8], whh0f[8], wih1f[8], whh1f[8];
  #pragma unroll
  for (int i = 0; i < 8; ++i){
    int vg = i*16 + lr;
    int g  = (vg & 3)*32 + (vg >> 2);
    float sc = ((vg & 3) == 2) ? LOG2E2 : LOG2E;
    union{bf16x8 v; u16 s[8];} a, b, c, d;
    #pragma unroll
    for (int j = 0; j < 8; ++j){
      int col = 4*j + kq;               // pi(kq*8+j) = 4j+kq
      a.s[j] = f2b(ws[g*32 + col]*sc);          // Wcomb
      b.s[j] = f2b(Whh0[g*32 + col]*sc);
      c.s[j] = f2b(Wih1[g*32 + col]*sc);
      d.s[j] = f2b(Whh1[g*32 + col]*sc);
    }
    wcombf[i] = a.v; whh0f[i] = b.v; wih1f[i] = c.v; whh1f[i] = d.v;
  }

  // ---- h_init = Wfc@latent + bfc, packed pi-style (elem j = unit 4j+kq) ----
  float hinit[8];
  {
    const float* lp = lat + (size_t)(ebase + lr)*16;
    float lv[16];
    #pragma unroll
    for (int j = 0; j < 16; ++j) lv[j] = lp[j];
    #pragma unroll
    for (int j = 0; j < 8; ++j){
      int u = 4*j + kq;
      const float* wf = Wfc + u*16;
      float a = bfc[u];
      #pragma unroll
      for (int p = 0; p < 16; ++p) a = fmaf(wf[p], lv[p], a);
      hinit[j] = a;
    }
  }
  bf16x8 h0f  = packh(hinit);   // h0(0-) = h_init
  bf16x8 h1hf = h0f;            // h1(0-) = h_init
  bf16x8 h1lof;
  { union{bf16x8 v; u16 s[8];} z; 
    #pragma unroll
    for (int j = 0; j < 8; ++j) z.s[j] = 0;
    h1lof = z.v; }

  float c0a[8] = {0,0,0,0,0,0,0,0};
  float c1a[8] = {0,0,0,0,0,0,0,0};

  #pragma unroll 1
  for (int t = 0; t < PRED; ++t){
    float h0n[8];
    if (t == 0){
      // gates0(0) = Wih0 . x0 (natural order) + Whh0_pi . h_init + b00
      bf16x8 bx[3];
      const float* xr = obs + ((size_t)15*BATCH + ebase + lr)*96;
      #pragma unroll
      for (int c = 0; c < 3; ++c){
        union{bf16x8 v; u16 s[8];} fr;
        const float* s8 = xr + c*32 + kq*8;
        #pragma unroll
        for (int j = 0; j < 8; ++j) fr.s[j] = f2b(s8[j]);
        bx[c] = fr.v;
      }
      #pragma unroll
      for (int i = 0; i < 8; ++i){
        int vg = i*16 + lr;
        int g  = (vg & 3)*32 + (vg >> 2);
        float sc = ((vg & 3) == 2) ? LOG2E2 : LOG2E;
        f32x4 acc = *(const f32x4*)&sm.b00[i*16 + kq*4];
        #pragma unroll
        for (int c = 0; c < 3; ++c){
          union{bf16x8 v; u16 s[8];} fr;
          const float* s8 = Wih0 + g*96 + c*32 + kq*8;
          #pragma unroll
          for (int j = 0; j < 8; ++j) fr.s[j] = f2b(s8[j]*sc);
          acc = __builtin_amdgcn_mfma_f32_16x16x32_bf16(fr.v, bx[c], acc, 0, 0, 0);
        }
        acc = __builtin_amdgcn_mfma_f32_16x16x32_bf16(whh0f[i], h0f, acc, 0, 0, 0);
        h0n[i] = act_h(acc, c0a[i]);
      }
    } else {
      // gates0(t) = Wcomb_pi.(h1hi+h1lo) + Whh0_pi.h0 + bcomb
      #pragma unroll
      for (int i = 0; i < 8; ++i){
        f32x4 acc = *(const f32x4*)&sm.bcomb[i*16 + kq*4];
        acc = __builtin_amdgcn_mfma_f32_16x16x32_bf16(wcombf[i], h1hf,  acc, 0, 0, 0);
        acc = __builtin_amdgcn_mfma_f32_16x16x32_bf16(wcombf[i], h1lof, acc, 0, 0, 0);
        acc = __builtin_amdgcn_mfma_f32_16x16x32_bf16(whh0f[i],  h0f,   acc, 0, 0, 0);
        h0n[i] = act_h(acc, c0a[i]);
      }
    }
    bf16x8 h0nf = packh(h0n);
    // gates1 = Wih1_pi . h0_new + Whh1_pi . h1_prev + b1
    float h1n[8];
    #pragma unroll
    for (int i = 0; i < 8; ++i){
      f32x4 acc = *(const f32x4*)&sm.b1[i*16 + kq*4];
      acc = __builtin_amdgcn_mfma_f32_16x16x32_bf16(wih1f[i], h0nf, acc, 0, 0, 0);
      acc = __builtin_amdgcn_mfma_f32_16x16x32_bf16(whh1f[i], h1hf, acc, 0, 0, 0);
      h1n[i] = act_h(acc, c1a[i]);
    }
    h0f = h0nf;
    pack_hilo(h1n, h1hf, h1lof);   // after gates1 consumed h1_prev
    // MLP (off-chain): out[t] = Wm_pi.(h1hi+h1lo) + bm ; direct f32x4 stores
    float* ob = out + (size_t)t*BATCH*96 + (size_t)(ebase + lr)*96;
    #pragma unroll
    for (int im = 0; im < 6; ++im){
      bf16x8 wmv = *(const bf16x8*)&sm.wmf[(im*64 + l)*8];
      f32x4 acc = *(const f32x4*)&sm.bm[im*16 + kq*4];
      acc = __builtin_amdgcn_mfma_f32_16x16x32_bf16(wmv, h1hf,  acc, 0, 0, 0);
      acc = __builtin_amdgcn_mfma_f32_16x16x32_bf16(wmv, h1lof, acc, 0, 0, 0);
      *(f32x4*)(ob + im*16 + kq*4) = acc;
    }
  }
}

extern "C" void kernel_launch(void* const* d_in, const int* in_sizes, int n_in,
                              void* d_out, int out_size, void* d_ws, size_t ws_size,
                              hipStream_t stream){
  const float* obs  = (const float*)d_in[0];
  const float* lat  = (const float*)d_in[1];
  const float* Wfc  = (const float*)d_in[3];
  const float* bfc  = (const float*)d_in[4];
  const float* Wih0 = (const float*)d_in[5];
  const float* Whh0 = (const float*)d_in[6];
  const float* bih0 = (const float*)d_in[7];
  const float* bhh0 = (const float*)d_in[8];
  const float* Wih1 = (const float*)d_in[9];
  const float* Whh1 = (const float*)d_in[10];
  const float* bih1 = (const float*)d_in[11];
  const float* bhh1 = (const float*)d_in[12];
  const float* Wmlp = (const float*)d_in[13];
  const float* bmlp = (const float*)d_in[14];
  float* ws = (float*)d_ws;

  prep_kernel<<<dim3(17), dim3(256), 0, stream>>>(Wih0, Wmlp, bih0, bhh0, bmlp, ws);
  decoder_kernel<<<dim3(BATCH/16), dim3(64), 0, stream>>>(
      obs, lat, Wfc, bfc, Wih0, Whh0, bih0, bhh0,
      Wih1, Whh1, bih1, bhh1, Wmlp, bmlp, ws, (float*)d_out);
}